// Round 1
// baseline (1133.292 us; speedup 1.0000x reference)
//
#include <hip/hip_runtime.h>
#include <cstdint>
#include <cstddef>

typedef short bf16x8 __attribute__((ext_vector_type(8)));
typedef float f32x4 __attribute__((ext_vector_type(4)));

__device__ __forceinline__ unsigned short f2bf(float f) {
  union { float f; unsigned u; } v; v.f = f;
  unsigned r = v.u + 0x7fffu + ((v.u >> 16) & 1u);
  return (unsigned short)(r >> 16);
}

// ---------------- cast fp32 -> bf16 (4 elems/thread) ----------------
__global__ __launch_bounds__(256) void cast_bf16(const float* __restrict__ in,
                                                 unsigned short* __restrict__ out, int n4) {
  int i = blockIdx.x * 256 + threadIdx.x;
  if (i < n4) {
    float4 v = ((const float4*)in)[i];
    ushort4 o;
    o.x = f2bf(v.x); o.y = f2bf(v.y); o.z = f2bf(v.z); o.w = f2bf(v.w);
    ((ushort4*)out)[i] = o;
  }
}

// ---------------- im2col for conv1 ----------------
// A1[m][k]: m = n*196 + oh*14 + ow   (M=12544)
//           k = ci*9 + kh*3 + kw     (K=4608)
// 4 consecutive k per thread; total threads = 12544*1152 (exact grid)
__global__ __launch_bounds__(256) void im2col1(const float* __restrict__ x,
                                               unsigned short* __restrict__ A1) {
  unsigned idx = blockIdx.x * 256u + threadIdx.x;   // < 14,450,688
  unsigned m = idx / 1152u;
  unsigned g = idx - m * 1152u;
  unsigned n = m / 196u;
  unsigned rem = m - n * 196u;
  unsigned oh = rem / 14u, ow = rem - (rem / 14u) * 14u;
  int ih0 = (int)oh * 3 - 1, iw0 = (int)ow * 3 - 1;
  ushort4 o;
  unsigned short vals[4];
  int k = (int)g * 4;
#pragma unroll
  for (int j = 0; j < 4; ++j) {
    int kk = k + j;
    int ci = kk / 9, r = kk - ci * 9;
    int kh = r / 3, kw = r - kh * 3;
    int ih = ih0 + kh, iw = iw0 + kw;
    float v = 0.f;
    if ((unsigned)ih < 40u && (unsigned)iw < 40u)
      v = x[(((size_t)n * 512 + ci) * 40 + ih) * 40 + iw];
    vals[j] = f2bf(v);
  }
  o.x = vals[0]; o.y = vals[1]; o.z = vals[2]; o.w = vals[3];
  ((ushort4*)A1)[idx] = o;
}

// ---------------- im2col for conv2 (applies BN1 scale/shift) ----------------
// A2[m][k]: m = n*25 + oh*5 + ow (M=1600), k = ci*9+kh*3+kw (K=2304)
// input C1[m1][256], m1 = n*196 + ih*14 + iw
__global__ __launch_bounds__(256) void im2col2(const float* __restrict__ C1,
                                               const float* __restrict__ scale,
                                               const float* __restrict__ shift,
                                               unsigned short* __restrict__ A2) {
  unsigned idx = blockIdx.x * 256u + threadIdx.x;  // < 3,686,400
  unsigned m = idx / 2304u;
  unsigned k = idx - m * 2304u;
  unsigned n = m / 25u, sp = m - n * 25u;
  unsigned oh = sp / 5u, ow = sp - oh * 5u;
  int ci = (int)(k / 9u); int r = (int)k - ci * 9;
  int kh = r / 3, kw = r - kh * 3;
  int ih = (int)oh * 3 - 1 + kh, iw = (int)ow * 3 - 1 + kw;
  float v = 0.f;
  if ((unsigned)ih < 14u && (unsigned)iw < 14u)
    v = C1[((size_t)n * 196 + ih * 14 + iw) * 256 + ci] * scale[ci] + shift[ci];
  A2[idx] = f2bf(v);
}

// ---------------- bf16 GEMM: C[M][N] = A[M][K] * B[N][K]^T ----------------
// BM=64 fixed; BN in {64,128}; block = 256 threads = 4 waves (2x2 wave grid)
// wave tile: 32(m) x BN/2(n); mfma_f32_16x16x32_bf16
template <int BN>
__global__ __launch_bounds__(256) void gemm_bf16(const unsigned short* __restrict__ A,
                                                 const unsigned short* __restrict__ B,
                                                 float* __restrict__ C,
                                                 int M, int N, int K) {
  __shared__ __align__(16) unsigned short As[64 * 32];
  __shared__ __align__(16) unsigned short Bs[BN * 32];
  constexpr int WN = BN / 2;
  constexpr int NT = WN / 16;
  int m0 = blockIdx.x * 64;
  int n0 = blockIdx.y * BN;
  int t = threadIdx.x;
  int wave = t >> 6, lane = t & 63;
  int q = lane >> 4, mr = lane & 15;
  int wm = (wave & 1) * 32;
  int wn = (wave >> 1) * WN;
  f32x4 acc[2][NT] = {};

  for (int k0 = 0; k0 < K; k0 += 32) {
    __syncthreads();
    // stage A tile 64x32 (one 16B chunk per thread)
    {
      const int4* ga = (const int4*)(A + (size_t)(m0 + (t >> 2)) * K + k0 + (t & 3) * 8);
      ((int4*)As)[t] = *ga;
    }
    // stage B tile BNx32
#pragma unroll
    for (int i = 0; i < BN / 64; ++i) {
      int c = t + i * 256;
      const int4* gb = (const int4*)(B + (size_t)(n0 + (c >> 2)) * K + k0 + (c & 3) * 8);
      ((int4*)Bs)[c] = *gb;
    }
    __syncthreads();
    bf16x8 af[2];
#pragma unroll
    for (int s = 0; s < 2; ++s)
      af[s] = *((const bf16x8*)(As + (wm + s * 16 + mr) * 32 + q * 8));
#pragma unroll
    for (int nt = 0; nt < NT; ++nt) {
      bf16x8 bfr = *((const bf16x8*)(Bs + (wn + nt * 16 + mr) * 32 + q * 8));
#pragma unroll
      for (int s = 0; s < 2; ++s)
        acc[s][nt] = __builtin_amdgcn_mfma_f32_16x16x32_bf16(af[s], bfr, acc[s][nt], 0, 0, 0);
    }
  }
  // C/D layout: row = q*4 + reg (M-dim), col = mr (N-dim)   [m89-verified]
#pragma unroll
  for (int s = 0; s < 2; ++s)
#pragma unroll
    for (int nt = 0; nt < NT; ++nt)
#pragma unroll
      for (int r = 0; r < 4; ++r)
        C[(size_t)(m0 + wm + s * 16 + q * 4 + r) * N + n0 + wn + nt * 16 + mr] = acc[s][nt][r];
}

// ---------------- BN stats: per-channel sum / sumsq ----------------
// blockDim.x == ncols; each block handles rowsPerBlock rows
__global__ void bn_stats(const float* __restrict__ C, float* __restrict__ sum,
                         float* __restrict__ sumsq, int rowsPerBlock, int ncols) {
  int c = threadIdx.x;
  int r0 = blockIdx.x * rowsPerBlock;
  float s = 0.f, s2 = 0.f;
  for (int r = 0; r < rowsPerBlock; ++r) {
    float v = C[(size_t)(r0 + r) * ncols + c];
    s += v; s2 += v * v;
  }
  atomicAdd(&sum[c], s);
  atomicAdd(&sumsq[c], s2);
}

__global__ void bn_scale(const float* __restrict__ sum, const float* __restrict__ sumsq,
                         const float* __restrict__ g, const float* __restrict__ b,
                         float* __restrict__ scale, float* __restrict__ shift,
                         float inv_count, int nc) {
  int c = blockIdx.x * blockDim.x + threadIdx.x;
  if (c < nc) {
    float m = sum[c] * inv_count;
    float var = sumsq[c] * inv_count - m * m;
    float sc = g[c] / sqrtf(var + 1e-5f);
    scale[c] = sc;
    shift[c] = b[c] - m * sc;
  }
}

// ---------------- MLP composition ----------------
// head: init r = w14 (len 2), c = b14; stages t=10..4 -> r len 256
__global__ void mlp_head(const float* w14, const float* b14,
                         const float* w13, const float* b13,
                         const float* w12, const float* b12,
                         const float* w11, const float* b11,
                         const float* w10, const float* b10,
                         const float* w9,  const float* b9,
                         const float* w8,  const float* b8,
                         const float* w7,  const float* b7,
                         float* __restrict__ r_out, float* __restrict__ c_out) {
  __shared__ float ra[256], rb[256];
  int t = threadIdx.x;
  float cs = 0.f;
  if (t < 2) ra[t] = w14[t];
  if (t == 0) cs = b14[0];
  __syncthreads();
  const float* Ws[7] = {w13, w12, w11, w10, w9, w8, w7};
  const float* Bs[7] = {b13, b12, b11, b10, b9, b8, b7};
  const int fouts[7] = {2, 4, 8, 16, 32, 64, 128};
  float* cur = ra; float* nxt = rb;
  for (int s = 0; s < 7; ++s) {
    int fo = fouts[s], fi = fo * 2;
    if (t == 0) {
      float d = 0.f;
      for (int i = 0; i < fo; ++i) d += cur[i] * Bs[s][i];
      cs += d;
    }
    if (t < fi) {
      float a = 0.f;
      const float* W = Ws[s];
      for (int i = 0; i < fo; ++i) a += cur[i] * W[i * fi + t];
      nxt[t] = a;
    }
    __syncthreads();
    float* tmp = cur; cur = nxt; nxt = tmp;
  }
  r_out[t] = cur[t];               // len 256
  if (t == 0) c_out[0] = cs;
}

// multi-block stage: r_out[j] = sum_i r_in[i]*W[i*fin+j]; block0 also c_out = c_in + r_in.b
// grid = fin/32 blocks, 256 threads (32 j-lanes x 8 i-groups); fout divisible by 8
__global__ void mlp_stage(const float* __restrict__ W, const float* __restrict__ bt,
                          const float* __restrict__ r_in, const float* __restrict__ c_in,
                          float* __restrict__ r_out, float* __restrict__ c_out,
                          int fin, int fout) {
  __shared__ float red[256];
  int t = threadIdx.x;
  int jl = t & 31, ig = t >> 5;
  int j = blockIdx.x * 32 + jl;
  int chunk = fout >> 3;
  int i0 = ig * chunk;
  float acc = 0.f;
  for (int i = i0; i < i0 + chunk; ++i)
    acc += r_in[i] * W[(size_t)i * fin + j];
  red[t] = acc;
  __syncthreads();
  if (ig == 0) {
    float s = 0.f;
#pragma unroll
    for (int u = 0; u < 8; ++u) s += red[u * 32 + jl];
    r_out[j] = s;
  }
  if (blockIdx.x == 0) {
    __syncthreads();
    float p = 0.f;
    for (int i = t; i < fout; i += 256) p += r_in[i] * bt[i];
    red[t] = p;
    __syncthreads();
    for (int s = 128; s > 0; s >>= 1) {
      if (t < s) red[t] += red[t + s];
      __syncthreads();
    }
    if (t == 0) c_out[0] = red[0] + c_in[0];
  }
}

// ---------------- final: BN2 + dot with composed vector + sigmoid ----------------
__global__ void final_k(const float* __restrict__ C2, const float* __restrict__ scale2,
                        const float* __restrict__ shift2, const float* __restrict__ r,
                        const float* __restrict__ c_in, float* __restrict__ out) {
  int n = blockIdx.x;       // 64
  int t = threadIdx.x;      // 256
  float acc = 0.f;
  for (int j = t; j < 3200; j += 256) {
    int c = j / 25, sp = j - c * 25;
    float v = C2[((size_t)n * 25 + sp) * 128 + c] * scale2[c] + shift2[c];
    acc += v * r[j];
  }
  __shared__ float red[256];
  red[t] = acc;
  __syncthreads();
  for (int s = 128; s > 0; s >>= 1) {
    if (t < s) red[t] += red[t + s];
    __syncthreads();
  }
  if (t == 0) {
    float z = red[0] + c_in[0];
    out[n] = 1.f / (1.f + expf(-z));
  }
}

// ---------------- workspace layout (bytes) ----------------
static constexpr size_t OFF_A1   = 0;                    // 12544*4608*2 = 115,605,504
static constexpr size_t OFF_W1B  = 115605504;            // 2,359,296
static constexpr size_t OFF_C1   = 117964800;            // 12,845,056
static constexpr size_t OFF_A2   = 130809856;            // 7,372,800
static constexpr size_t OFF_W2B  = 138182656;            // 589,824
static constexpr size_t OFF_C2   = 138772480;            // 819,200
static constexpr size_t OFF_SUM1 = 139591680;            // 1024
static constexpr size_t OFF_SQ1  = 139592704;
static constexpr size_t OFF_SUM2 = 139593728;
static constexpr size_t OFF_SQ2  = 139594752;
static constexpr size_t OFF_SC1  = 139595776;
static constexpr size_t OFF_SH1  = 139596800;
static constexpr size_t OFF_SC2  = 139597824;
static constexpr size_t OFF_SH2  = 139598848;
static constexpr size_t OFF_RA   = 139599872;            // 13056
static constexpr size_t OFF_RB   = 139612928;            // 13056
static constexpr size_t OFF_CA   = 139625984;            // 256
static constexpr size_t OFF_CB   = 139626240;            // 256

extern "C" void kernel_launch(void* const* d_in, const int* in_sizes, int n_in,
                              void* d_out, int out_size, void* d_ws, size_t ws_size,
                              hipStream_t stream) {
  const float* x   = (const float*)d_in[0];
  const float* w1  = (const float*)d_in[1];
  const float* g1  = (const float*)d_in[3];
  const float* bb1 = (const float*)d_in[4];
  const float* w2  = (const float*)d_in[5];
  const float* g2  = (const float*)d_in[7];
  const float* bb2 = (const float*)d_in[8];

  char* ws = (char*)d_ws;
  unsigned short* A1  = (unsigned short*)(ws + OFF_A1);
  unsigned short* W1b = (unsigned short*)(ws + OFF_W1B);
  float*          C1  = (float*)(ws + OFF_C1);
  unsigned short* A2  = (unsigned short*)(ws + OFF_A2);
  unsigned short* W2b = (unsigned short*)(ws + OFF_W2B);
  float*          C2  = (float*)(ws + OFF_C2);
  float* SUM1 = (float*)(ws + OFF_SUM1);
  float* SQ1  = (float*)(ws + OFF_SQ1);
  float* SUM2 = (float*)(ws + OFF_SUM2);
  float* SQ2  = (float*)(ws + OFF_SQ2);
  float* SC1  = (float*)(ws + OFF_SC1);
  float* SH1  = (float*)(ws + OFF_SH1);
  float* SC2  = (float*)(ws + OFF_SC2);
  float* SH2  = (float*)(ws + OFF_SH2);
  float* RA   = (float*)(ws + OFF_RA);
  float* RB   = (float*)(ws + OFF_RB);
  float* CA   = (float*)(ws + OFF_CA);
  float* CB   = (float*)(ws + OFF_CB);

  // zero the stats accumulators (SUM1,SQ1,SUM2,SQ2 are contiguous)
  hipMemsetAsync(ws + OFF_SUM1, 0, 4096, stream);

  // weight casts
  cast_bf16<<<1152, 256, 0, stream>>>(w1, W1b, 294912);   // 256*4608/4
  cast_bf16<<<288, 256, 0, stream>>>(w2, W2b, 73728);     // 128*2304/4

  // conv1 as GEMM
  im2col1<<<56448, 256, 0, stream>>>(x, A1);
  gemm_bf16<128><<<dim3(196, 2), 256, 0, stream>>>(A1, W1b, C1, 12544, 256, 4608);
  bn_stats<<<98, 256, 0, stream>>>(C1, SUM1, SQ1, 128, 256);
  bn_scale<<<1, 256, 0, stream>>>(SUM1, SQ1, g1, bb1, SC1, SH1, 1.f / 12544.f, 256);

  // conv2 as GEMM (BN1 applied in im2col2)
  im2col2<<<14400, 256, 0, stream>>>(C1, SC1, SH1, A2);
  gemm_bf16<64><<<dim3(25, 2), 256, 0, stream>>>(A2, W2b, C2, 1600, 128, 2304);
  bn_stats<<<16, 128, 0, stream>>>(C2, SUM2, SQ2, 100, 128);
  bn_scale<<<1, 256, 0, stream>>>(SUM2, SQ2, g2, bb2, SC2, SH2, 1.f / 1600.f, 128);

  // MLP composition: collapse 12 affine layers to (M, c)
  mlp_head<<<1, 256, 0, stream>>>(
      (const float*)d_in[31], (const float*)d_in[32],   // w14, b14
      (const float*)d_in[29], (const float*)d_in[30],   // w13, b13
      (const float*)d_in[27], (const float*)d_in[28],   // w12, b12
      (const float*)d_in[25], (const float*)d_in[26],   // w11, b11
      (const float*)d_in[23], (const float*)d_in[24],   // w10, b10
      (const float*)d_in[21], (const float*)d_in[22],   // w9,  b9
      (const float*)d_in[19], (const float*)d_in[20],   // w8,  b8
      (const float*)d_in[17], (const float*)d_in[18],   // w7,  b7
      RA, CA);
  mlp_stage<<<16, 256, 0, stream>>>((const float*)d_in[15], (const float*)d_in[16],
                                    RA, CA, RB, CB, 512, 256);    // w6
  mlp_stage<<<32, 256, 0, stream>>>((const float*)d_in[13], (const float*)d_in[14],
                                    RB, CB, RA, CA, 1024, 512);   // w5
  mlp_stage<<<64, 256, 0, stream>>>((const float*)d_in[11], (const float*)d_in[12],
                                    RA, CA, RB, CB, 2048, 1024);  // w4
  mlp_stage<<<100, 256, 0, stream>>>((const float*)d_in[9], (const float*)d_in[10],
                                     RB, CB, RA, CA, 3200, 2048); // w3

  final_k<<<64, 256, 0, stream>>>(C2, SC2, SH2, RA, CA, (float*)d_out);
}

// Round 2
// 936.210 us; speedup vs baseline: 1.2105x; 1.2105x over previous
//
#include <hip/hip_runtime.h>
#include <cstdint>
#include <cstddef>

typedef short bf16x8 __attribute__((ext_vector_type(8)));
typedef float f32x4 __attribute__((ext_vector_type(4)));

__device__ __forceinline__ unsigned short f2bf(float f) {
  union { float f; unsigned u; } v; v.f = f;
  unsigned r = v.u + 0x7fffu + ((v.u >> 16) & 1u);
  return (unsigned short)(r >> 16);
}

// async global->LDS 16B per lane; LDS dest = wave-uniform base + lane*16
#define GLOAD_LDS16(gp, lp)                                            \
  __builtin_amdgcn_global_load_lds(                                    \
      (const __attribute__((address_space(1))) void*)(const void*)(gp),\
      (__attribute__((address_space(3))) void*)(void*)(lp), 16, 0, 0)

// ---------------- cast fp32 -> bf16 (4 elems/thread) ----------------
__global__ __launch_bounds__(256) void cast_bf16(const float* __restrict__ in,
                                                 unsigned short* __restrict__ out, int n4) {
  int i = blockIdx.x * 256 + threadIdx.x;
  if (i < n4) {
    float4 v = ((const float4*)in)[i];
    ushort4 o;
    o.x = f2bf(v.x); o.y = f2bf(v.y); o.z = f2bf(v.z); o.w = f2bf(v.w);
    ((ushort4*)out)[i] = o;
  }
}

// ---------------- im2col for conv1 (LDS-staged, coalesced both sides) -------
// grid: (ci_chunk=8, oh=14, n=64); block 256.
// LDS buf[c][r][42] zero-padded at iw=-1 and iw=40; value(c,kh,iw) = buf[c][kh][iw+1]
// A1[m][k]: m = n*196 + oh*14 + ow, k = ci*9 + kh*3 + kw
__global__ __launch_bounds__(256) void im2col1(const float* __restrict__ x,
                                               unsigned short* __restrict__ A1) {
  __shared__ float buf[64 * 126];   // 32,256 B
  int t = threadIdx.x;
  int cc = blockIdx.x, oh = blockIdx.y, n = blockIdx.z;
  int ci0 = cc * 64;
  int ih0 = oh * 3 - 1;
  // zero the pad columns
  for (int rowid = t; rowid < 192; rowid += 256) {
    int c = rowid / 3, r = rowid - c * 3;
    buf[c * 126 + r * 42 + 0] = 0.f;
    buf[c * 126 + r * 42 + 41] = 0.f;
  }
  // load 192 rows x 40 floats, contiguous float4 per lane
  for (int idx = t; idx < 1920; idx += 256) {
    int row = idx / 10, ch = idx - row * 10;
    int c = row / 3, r = row - c * 3;
    int ih = ih0 + r;
    float4 v = make_float4(0.f, 0.f, 0.f, 0.f);
    if ((unsigned)ih < 40u)
      v = *(const float4*)(x + (((size_t)n * 512 + ci0 + c) * 40 + ih) * 40 + ch * 4);
    float* dst = buf + c * 126 + r * 42 + 1 + ch * 4;
    dst[0] = v.x; dst[1] = v.y; dst[2] = v.z; dst[3] = v.w;
  }
  __syncthreads();
  // emit 14 rows x 576 k (ushort4 per lane, coalesced)
  for (int idx = t; idx < 2016; idx += 256) {
    int ow = idx / 144, q4 = idx - ow * 144;
    int kk = q4 * 4;
    unsigned short vv[4];
#pragma unroll
    for (int j = 0; j < 4; ++j) {
      int k = kk + j;
      int c = k / 9, rr = k - c * 9;
      int kh = rr / 3, kw = rr - kh * 3;
      vv[j] = f2bf(buf[c * 126 + kh * 42 + 3 * ow + kw]);
    }
    ushort4 o; o.x = vv[0]; o.y = vv[1]; o.z = vv[2]; o.w = vv[3];
    *(ushort4*)(A1 + ((size_t)(n * 196 + oh * 14 + ow)) * 4608 + cc * 576 + kk) = o;
  }
}

// ---------------- im2col for conv2 (applies BN1 scale/shift) ----------------
__global__ __launch_bounds__(256) void im2col2(const float* __restrict__ C1,
                                               const float* __restrict__ scale,
                                               const float* __restrict__ shift,
                                               unsigned short* __restrict__ A2) {
  unsigned idx = blockIdx.x * 256u + threadIdx.x;  // < 3,686,400
  unsigned m = idx / 2304u;
  unsigned k = idx - m * 2304u;
  unsigned n = m / 25u, sp = m - n * 25u;
  unsigned oh = sp / 5u, ow = sp - oh * 5u;
  int ci = (int)(k / 9u); int r = (int)k - ci * 9;
  int kh = r / 3, kw = r - kh * 3;
  int ih = (int)oh * 3 - 1 + kh, iw = (int)ow * 3 - 1 + kw;
  float v = 0.f;
  if ((unsigned)ih < 14u && (unsigned)iw < 14u)
    v = C1[((size_t)n * 196 + ih * 14 + iw) * 256 + ci] * scale[ci] + shift[ci];
  A2[idx] = f2bf(v);
}

// ---------------- bf16 GEMM: C[M][N] = A[M][K] * B[N][K]^T ----------------
// BM=64; BN in {64,128}; 256 threads = 4 waves (2x2); global_load_lds staging
template <int BN>
__global__ __launch_bounds__(256) void gemm_bf16(const unsigned short* __restrict__ A,
                                                 const unsigned short* __restrict__ B,
                                                 float* __restrict__ C,
                                                 int M, int N, int K) {
  __shared__ __align__(16) unsigned short As[64 * 32];
  __shared__ __align__(16) unsigned short Bs[BN * 32];
  constexpr int WN = BN / 2;
  constexpr int NT = WN / 16;
  int m0 = blockIdx.x * 64;
  int n0 = blockIdx.y * BN;
  int t = threadIdx.x;
  int wave = t >> 6, lane = t & 63;
  (void)wave; (void)lane;
  int q = (t & 63) >> 4, mr = t & 15;
  int wm = ((t >> 6) & 1) * 32;
  int wn = (t >> 7) * WN;
  f32x4 acc[2][NT] = {};

  for (int k0 = 0; k0 < K; k0 += 32) {
    __syncthreads();
    // A tile 64x32: chunk c = t; LDS byte offset c*16 == row-major layout
    GLOAD_LDS16(A + (size_t)(m0 + (t >> 2)) * K + k0 + (t & 3) * 8, As + t * 8);
    // B tile BNx32
#pragma unroll
    for (int i = 0; i < BN / 64; ++i) {
      int c = t + i * 256;
      GLOAD_LDS16(B + (size_t)(n0 + (c >> 2)) * K + k0 + (c & 3) * 8, Bs + c * 8);
    }
    __syncthreads();   // drains vmcnt for global_load_lds
    bf16x8 af[2];
#pragma unroll
    for (int s = 0; s < 2; ++s)
      af[s] = *((const bf16x8*)(As + (wm + s * 16 + mr) * 32 + q * 8));
#pragma unroll
    for (int nt = 0; nt < NT; ++nt) {
      bf16x8 bfr = *((const bf16x8*)(Bs + (wn + nt * 16 + mr) * 32 + q * 8));
#pragma unroll
      for (int s = 0; s < 2; ++s)
        acc[s][nt] = __builtin_amdgcn_mfma_f32_16x16x32_bf16(af[s], bfr, acc[s][nt], 0, 0, 0);
    }
  }
  // C/D layout: row = q*4 + reg (M-dim), col = mr (N-dim)   [m89-verified]
#pragma unroll
  for (int s = 0; s < 2; ++s)
#pragma unroll
    for (int nt = 0; nt < NT; ++nt)
#pragma unroll
      for (int r = 0; r < 4; ++r)
        C[(size_t)(m0 + wm + s * 16 + q * 4 + r) * N + n0 + wn + nt * 16 + mr] = acc[s][nt][r];
}

// ---------------- BN stats: per-channel sum / sumsq ----------------
__global__ void bn_stats(const float* __restrict__ C, float* __restrict__ sum,
                         float* __restrict__ sumsq, int rowsPerBlock, int ncols) {
  int c = threadIdx.x;
  int r0 = blockIdx.x * rowsPerBlock;
  float s = 0.f, s2 = 0.f;
  for (int r = 0; r < rowsPerBlock; ++r) {
    float v = C[(size_t)(r0 + r) * ncols + c];
    s += v; s2 += v * v;
  }
  atomicAdd(&sum[c], s);
  atomicAdd(&sumsq[c], s2);
}

__global__ void bn_scale(const float* __restrict__ sum, const float* __restrict__ sumsq,
                         const float* __restrict__ g, const float* __restrict__ b,
                         float* __restrict__ scale, float* __restrict__ shift,
                         float inv_count, int nc) {
  int c = blockIdx.x * blockDim.x + threadIdx.x;
  if (c < nc) {
    float m = sum[c] * inv_count;
    float var = sumsq[c] * inv_count - m * m;
    float sc = g[c] / sqrtf(var + 1e-5f);
    scale[c] = sc;
    shift[c] = b[c] - m * sc;
  }
}

// ---------------- MLP composition ----------------
__global__ void mlp_head(const float* w14, const float* b14,
                         const float* w13, const float* b13,
                         const float* w12, const float* b12,
                         const float* w11, const float* b11,
                         const float* w10, const float* b10,
                         const float* w9,  const float* b9,
                         const float* w8,  const float* b8,
                         const float* w7,  const float* b7,
                         float* __restrict__ r_out, float* __restrict__ c_out) {
  __shared__ float ra[256], rb[256];
  int t = threadIdx.x;
  float cs = 0.f;
  if (t < 2) ra[t] = w14[t];
  if (t == 0) cs = b14[0];
  __syncthreads();
  const float* Ws[7] = {w13, w12, w11, w10, w9, w8, w7};
  const float* Bs[7] = {b13, b12, b11, b10, b9, b8, b7};
  const int fouts[7] = {2, 4, 8, 16, 32, 64, 128};
  float* cur = ra; float* nxt = rb;
  for (int s = 0; s < 7; ++s) {
    int fo = fouts[s], fi = fo * 2;
    if (t == 0) {
      float d = 0.f;
      for (int i = 0; i < fo; ++i) d += cur[i] * Bs[s][i];
      cs += d;
    }
    if (t < fi) {
      float a = 0.f;
      const float* W = Ws[s];
      for (int i = 0; i < fo; ++i) a += cur[i] * W[i * fi + t];
      nxt[t] = a;
    }
    __syncthreads();
    float* tmp = cur; cur = nxt; nxt = tmp;
  }
  r_out[t] = cur[t];               // len 256
  if (t == 0) c_out[0] = cs;
}

__global__ void mlp_stage(const float* __restrict__ W, const float* __restrict__ bt,
                          const float* __restrict__ r_in, const float* __restrict__ c_in,
                          float* __restrict__ r_out, float* __restrict__ c_out,
                          int fin, int fout) {
  __shared__ float red[256];
  int t = threadIdx.x;
  int jl = t & 31, ig = t >> 5;
  int j = blockIdx.x * 32 + jl;
  int chunk = fout >> 3;
  int i0 = ig * chunk;
  float acc = 0.f;
  for (int i = i0; i < i0 + chunk; ++i)
    acc += r_in[i] * W[(size_t)i * fin + j];
  red[t] = acc;
  __syncthreads();
  if (ig == 0) {
    float s = 0.f;
#pragma unroll
    for (int u = 0; u < 8; ++u) s += red[u * 32 + jl];
    r_out[j] = s;
  }
  if (blockIdx.x == 0) {
    __syncthreads();
    float p = 0.f;
    for (int i = t; i < fout; i += 256) p += r_in[i] * bt[i];
    red[t] = p;
    __syncthreads();
    for (int s = 128; s > 0; s >>= 1) {
      if (t < s) red[t] += red[t + s];
      __syncthreads();
    }
    if (t == 0) c_out[0] = red[0] + c_in[0];
  }
}

// ---------------- final: BN2 + dot with composed vector + sigmoid ----------------
__global__ void final_k(const float* __restrict__ C2, const float* __restrict__ scale2,
                        const float* __restrict__ shift2, const float* __restrict__ r,
                        const float* __restrict__ c_in, float* __restrict__ out) {
  int n = blockIdx.x;       // 64
  int t = threadIdx.x;      // 256
  float acc = 0.f;
  for (int j = t; j < 3200; j += 256) {
    int c = j / 25, sp = j - c * 25;
    float v = C2[((size_t)n * 25 + sp) * 128 + c] * scale2[c] + shift2[c];
    acc += v * r[j];
  }
  __shared__ float red[256];
  red[t] = acc;
  __syncthreads();
  for (int s = 128; s > 0; s >>= 1) {
    if (t < s) red[t] += red[t + s];
    __syncthreads();
  }
  if (t == 0) {
    float z = red[0] + c_in[0];
    out[n] = 1.f / (1.f + expf(-z));
  }
}

// ---------------- workspace layout (bytes) ----------------
static constexpr size_t OFF_A1   = 0;                    // 115,605,504
static constexpr size_t OFF_W1B  = 115605504;            // 2,359,296
static constexpr size_t OFF_C1   = 117964800;            // 12,845,056
static constexpr size_t OFF_A2   = 130809856;            // 7,372,800
static constexpr size_t OFF_W2B  = 138182656;            // 589,824
static constexpr size_t OFF_C2   = 138772480;            // 819,200
static constexpr size_t OFF_SUM1 = 139591680;
static constexpr size_t OFF_SQ1  = 139592704;
static constexpr size_t OFF_SUM2 = 139593728;
static constexpr size_t OFF_SQ2  = 139594752;
static constexpr size_t OFF_SC1  = 139595776;
static constexpr size_t OFF_SH1  = 139596800;
static constexpr size_t OFF_SC2  = 139597824;
static constexpr size_t OFF_SH2  = 139598848;
static constexpr size_t OFF_RA   = 139599872;
static constexpr size_t OFF_RB   = 139612928;
static constexpr size_t OFF_CA   = 139625984;
static constexpr size_t OFF_CB   = 139626240;

extern "C" void kernel_launch(void* const* d_in, const int* in_sizes, int n_in,
                              void* d_out, int out_size, void* d_ws, size_t ws_size,
                              hipStream_t stream) {
  const float* x   = (const float*)d_in[0];
  const float* w1  = (const float*)d_in[1];
  const float* g1  = (const float*)d_in[3];
  const float* bb1 = (const float*)d_in[4];
  const float* w2  = (const float*)d_in[5];
  const float* g2  = (const float*)d_in[7];
  const float* bb2 = (const float*)d_in[8];

  char* ws = (char*)d_ws;
  unsigned short* A1  = (unsigned short*)(ws + OFF_A1);
  unsigned short* W1b = (unsigned short*)(ws + OFF_W1B);
  float*          C1  = (float*)(ws + OFF_C1);
  unsigned short* A2  = (unsigned short*)(ws + OFF_A2);
  unsigned short* W2b = (unsigned short*)(ws + OFF_W2B);
  float*          C2  = (float*)(ws + OFF_C2);
  float* SUM1 = (float*)(ws + OFF_SUM1);
  float* SQ1  = (float*)(ws + OFF_SQ1);
  float* SUM2 = (float*)(ws + OFF_SUM2);
  float* SQ2  = (float*)(ws + OFF_SQ2);
  float* SC1  = (float*)(ws + OFF_SC1);
  float* SH1  = (float*)(ws + OFF_SH1);
  float* SC2  = (float*)(ws + OFF_SC2);
  float* SH2  = (float*)(ws + OFF_SH2);
  float* RA   = (float*)(ws + OFF_RA);
  float* RB   = (float*)(ws + OFF_RB);
  float* CA   = (float*)(ws + OFF_CA);
  float* CB   = (float*)(ws + OFF_CB);

  hipMemsetAsync(ws + OFF_SUM1, 0, 4096, stream);

  cast_bf16<<<1152, 256, 0, stream>>>(w1, W1b, 294912);
  cast_bf16<<<288, 256, 0, stream>>>(w2, W2b, 73728);

  // conv1 as GEMM
  im2col1<<<dim3(8, 14, 64), 256, 0, stream>>>(x, A1);
  gemm_bf16<128><<<dim3(196, 2), 256, 0, stream>>>(A1, W1b, C1, 12544, 256, 4608);
  bn_stats<<<98, 256, 0, stream>>>(C1, SUM1, SQ1, 128, 256);
  bn_scale<<<1, 256, 0, stream>>>(SUM1, SQ1, g1, bb1, SC1, SH1, 1.f / 12544.f, 256);

  // conv2 as GEMM (BN1 applied in im2col2)
  im2col2<<<14400, 256, 0, stream>>>(C1, SC1, SH1, A2);
  gemm_bf16<64><<<dim3(25, 2), 256, 0, stream>>>(A2, W2b, C2, 1600, 128, 2304);
  bn_stats<<<16, 128, 0, stream>>>(C2, SUM2, SQ2, 100, 128);
  bn_scale<<<1, 256, 0, stream>>>(SUM2, SQ2, g2, bb2, SC2, SH2, 1.f / 1600.f, 128);

  // MLP composition
  mlp_head<<<1, 256, 0, stream>>>(
      (const float*)d_in[31], (const float*)d_in[32],
      (const float*)d_in[29], (const float*)d_in[30],
      (const float*)d_in[27], (const float*)d_in[28],
      (const float*)d_in[25], (const float*)d_in[26],
      (const float*)d_in[23], (const float*)d_in[24],
      (const float*)d_in[21], (const float*)d_in[22],
      (const float*)d_in[19], (const float*)d_in[20],
      (const float*)d_in[17], (const float*)d_in[18],
      RA, CA);
  mlp_stage<<<16, 256, 0, stream>>>((const float*)d_in[15], (const float*)d_in[16],
                                    RA, CA, RB, CB, 512, 256);
  mlp_stage<<<32, 256, 0, stream>>>((const float*)d_in[13], (const float*)d_in[14],
                                    RB, CB, RA, CA, 1024, 512);
  mlp_stage<<<64, 256, 0, stream>>>((const float*)d_in[11], (const float*)d_in[12],
                                    RA, CA, RB, CB, 2048, 1024);
  mlp_stage<<<100, 256, 0, stream>>>((const float*)d_in[9], (const float*)d_in[10],
                                     RB, CB, RA, CA, 3200, 2048);

  final_k<<<64, 256, 0, stream>>>(C2, SC2, SH2, RA, CA, (float*)d_out);
}

// Round 3
// 849.142 us; speedup vs baseline: 1.3346x; 1.1025x over previous
//
#include <hip/hip_runtime.h>
#include <cstdint>
#include <cstddef>

typedef short bf16x8 __attribute__((ext_vector_type(8)));
typedef float f32x4 __attribute__((ext_vector_type(4)));

__device__ __forceinline__ unsigned short f2bf(float f) {
  union { float f; unsigned u; } v; v.f = f;
  unsigned r = v.u + 0x7fffu + ((v.u >> 16) & 1u);
  return (unsigned short)(r >> 16);
}

// async global->LDS 16B per lane; LDS dest = wave-uniform base + lane*16
#define GLOAD_LDS16(gp, lp)                                            \
  __builtin_amdgcn_global_load_lds(                                    \
      (const __attribute__((address_space(1))) void*)(const void*)(gp),\
      (__attribute__((address_space(3))) void*)(void*)(lp), 16, 0, 0)

// ---------------- cast both conv weights fp32 -> bf16 ----------------
// w1: 294912 float4 chunks, w2: 73728 chunks
__global__ __launch_bounds__(256) void cast2(const float* __restrict__ w1,
                                             const float* __restrict__ w2,
                                             unsigned short* __restrict__ W1b,
                                             unsigned short* __restrict__ W2b) {
  int i = blockIdx.x * 256 + threadIdx.x;
  const float* src; unsigned short* dst; int j;
  if (i < 294912) { src = w1; dst = W1b; j = i; }
  else if (i < 368640) { src = w2; dst = W2b; j = i - 294912; }
  else return;
  float4 v = ((const float4*)src)[j];
  ushort4 o;
  o.x = f2bf(v.x); o.y = f2bf(v.y); o.z = f2bf(v.z); o.w = f2bf(v.w);
  ((ushort4*)dst)[j] = o;
}

// ---------------- im2col for conv1 (LDS-staged, coalesced both sides) -------
// grid: (ci_chunk=8, oh=14, n=64); block 256.
__global__ __launch_bounds__(256) void im2col1(const float* __restrict__ x,
                                               unsigned short* __restrict__ A1) {
  __shared__ float buf[64 * 126];   // 32,256 B
  int t = threadIdx.x;
  int cc = blockIdx.x, oh = blockIdx.y, n = blockIdx.z;
  int ci0 = cc * 64;
  int ih0 = oh * 3 - 1;
  for (int rowid = t; rowid < 192; rowid += 256) {
    int c = rowid / 3, r = rowid - c * 3;
    buf[c * 126 + r * 42 + 0] = 0.f;
    buf[c * 126 + r * 42 + 41] = 0.f;
  }
  for (int idx = t; idx < 1920; idx += 256) {
    int row = idx / 10, ch = idx - row * 10;
    int c = row / 3, r = row - c * 3;
    int ih = ih0 + r;
    float4 v = make_float4(0.f, 0.f, 0.f, 0.f);
    if ((unsigned)ih < 40u)
      v = *(const float4*)(x + (((size_t)n * 512 + ci0 + c) * 40 + ih) * 40 + ch * 4);
    float* dst = buf + c * 126 + r * 42 + 1 + ch * 4;
    dst[0] = v.x; dst[1] = v.y; dst[2] = v.z; dst[3] = v.w;
  }
  __syncthreads();
  for (int idx = t; idx < 2016; idx += 256) {
    int ow = idx / 144, q4 = idx - ow * 144;
    int kk = q4 * 4;
    unsigned short vv[4];
#pragma unroll
    for (int j = 0; j < 4; ++j) {
      int k = kk + j;
      int c = k / 9, rr = k - c * 9;
      int kh = rr / 3, kw = rr - kh * 3;
      vv[j] = f2bf(buf[c * 126 + kh * 42 + 3 * ow + kw]);
    }
    ushort4 o; o.x = vv[0]; o.y = vv[1]; o.z = vv[2]; o.w = vv[3];
    *(ushort4*)(A1 + ((size_t)(n * 196 + oh * 14 + ow)) * 4608 + cc * 576 + kk) = o;
  }
}

// ---------------- im2col for conv2 (BN1 scale/shift computed inline) --------
__global__ __launch_bounds__(256) void im2col2(const float* __restrict__ C1,
                                               const float* __restrict__ SUM1,
                                               const float* __restrict__ SQ1,
                                               const float* __restrict__ g,
                                               const float* __restrict__ b,
                                               unsigned short* __restrict__ A2) {
  unsigned idx = blockIdx.x * 256u + threadIdx.x;  // < 3,686,400
  unsigned m = idx / 2304u;
  unsigned k = idx - m * 2304u;
  unsigned n = m / 25u, sp = m - n * 25u;
  unsigned oh = sp / 5u, ow = sp - oh * 5u;
  int ci = (int)(k / 9u); int r = (int)k - ci * 9;
  int kh = r / 3, kw = r - kh * 3;
  int ih = (int)oh * 3 - 1 + kh, iw = (int)ow * 3 - 1 + kw;
  float v = 0.f;
  if ((unsigned)ih < 14u && (unsigned)iw < 14u) {
    float mean = SUM1[ci] * (1.f / 12544.f);
    float var = SQ1[ci] * (1.f / 12544.f) - mean * mean;
    float sc = g[ci] / sqrtf(var + 1e-5f);
    float sh = b[ci] - mean * sc;
    v = C1[((size_t)n * 196 + ih * 14 + iw) * 256 + ci] * sc + sh;
  }
  A2[idx] = f2bf(v);
}

// ---------------- bf16 GEMM with K-split: Cp[z] = A*B^T over k-chunk --------
// BM=64; BN in {64,128}; 256 threads = 4 waves (2x2); global_load_lds staging
template <int BN>
__global__ __launch_bounds__(256) void gemm_bf16(const unsigned short* __restrict__ A,
                                                 const unsigned short* __restrict__ B,
                                                 float* __restrict__ Cp,
                                                 int M, int N, int K, int k_chunk) {
  __shared__ __align__(16) unsigned short As[64 * 32];
  __shared__ __align__(16) unsigned short Bs[BN * 32];
  constexpr int WN = BN / 2;
  constexpr int NT = WN / 16;
  int m0 = blockIdx.x * 64;
  int n0 = blockIdx.y * BN;
  int kb = blockIdx.z;
  Cp += (size_t)kb * M * N;
  int k_begin = kb * k_chunk;
  int t = threadIdx.x;
  int q = (t & 63) >> 4, mr = t & 15;
  int wm = ((t >> 6) & 1) * 32;
  int wn = (t >> 7) * WN;
  f32x4 acc[2][NT] = {};

  for (int k0 = k_begin; k0 < k_begin + k_chunk; k0 += 32) {
    __syncthreads();
    GLOAD_LDS16(A + (size_t)(m0 + (t >> 2)) * K + k0 + (t & 3) * 8, As + t * 8);
#pragma unroll
    for (int i = 0; i < BN / 64; ++i) {
      int c = t + i * 256;
      GLOAD_LDS16(B + (size_t)(n0 + (c >> 2)) * K + k0 + (c & 3) * 8, Bs + c * 8);
    }
    __syncthreads();
    bf16x8 af[2];
#pragma unroll
    for (int s = 0; s < 2; ++s)
      af[s] = *((const bf16x8*)(As + (wm + s * 16 + mr) * 32 + q * 8));
#pragma unroll
    for (int nt = 0; nt < NT; ++nt) {
      bf16x8 bfr = *((const bf16x8*)(Bs + (wn + nt * 16 + mr) * 32 + q * 8));
#pragma unroll
      for (int s = 0; s < 2; ++s)
        acc[s][nt] = __builtin_amdgcn_mfma_f32_16x16x32_bf16(af[s], bfr, acc[s][nt], 0, 0, 0);
    }
  }
  // C/D layout: row = q*4 + reg (M-dim), col = mr (N-dim)   [m89-verified]
#pragma unroll
  for (int s = 0; s < 2; ++s)
#pragma unroll
    for (int nt = 0; nt < NT; ++nt)
#pragma unroll
      for (int r = 0; r < 4; ++r)
        Cp[(size_t)(m0 + wm + s * 16 + q * 4 + r) * N + n0 + wn + nt * 16 + mr] = acc[s][nt][r];
}

// ---------------- reduce K-split partials + BN stats --------------------
// block: ncols threads; each block handles rowsPerBlock rows
template <int KS>
__global__ void reduce_stats(const float* __restrict__ Cp, float* __restrict__ C,
                             float* __restrict__ sum, float* __restrict__ sumsq,
                             int rowsPerBlock, int ncols, int MN) {
  int c = threadIdx.x;
  int r0 = blockIdx.x * rowsPerBlock;
  float s = 0.f, s2 = 0.f;
  for (int r = 0; r < rowsPerBlock; ++r) {
    size_t off = (size_t)(r0 + r) * ncols + c;
    float v = 0.f;
#pragma unroll
    for (int k = 0; k < KS; ++k) v += Cp[(size_t)k * MN + off];
    C[off] = v;
    s += v; s2 += v * v;
  }
  atomicAdd(&sum[c], s);
  atomicAdd(&sumsq[c], s2);
}

// ---------------- MLP composition ----------------
__global__ void mlp_head(const float* w14, const float* b14,
                         const float* w13, const float* b13,
                         const float* w12, const float* b12,
                         const float* w11, const float* b11,
                         const float* w10, const float* b10,
                         const float* w9,  const float* b9,
                         const float* w8,  const float* b8,
                         const float* w7,  const float* b7,
                         float* __restrict__ r_out, float* __restrict__ c_out) {
  __shared__ float ra[256], rb[256];
  int t = threadIdx.x;
  float cs = 0.f;
  if (t < 2) ra[t] = w14[t];
  if (t == 0) cs = b14[0];
  __syncthreads();
  const float* Ws[7] = {w13, w12, w11, w10, w9, w8, w7};
  const float* Bs[7] = {b13, b12, b11, b10, b9, b8, b7};
  const int fouts[7] = {2, 4, 8, 16, 32, 64, 128};
  float* cur = ra; float* nxt = rb;
  for (int s = 0; s < 7; ++s) {
    int fo = fouts[s], fi = fo * 2;
    if (t == 0) {
      float d = 0.f;
      for (int i = 0; i < fo; ++i) d += cur[i] * Bs[s][i];
      cs += d;
    }
    if (t < fi) {
      float a = 0.f;
      const float* W = Ws[s];
      for (int i = 0; i < fo; ++i) a += cur[i] * W[i * fi + t];
      nxt[t] = a;
    }
    __syncthreads();
    float* tmp = cur; cur = nxt; nxt = tmp;
  }
  r_out[t] = cur[t];               // len 256
  if (t == 0) c_out[0] = cs;
}

__global__ void mlp_stage(const float* __restrict__ W, const float* __restrict__ bt,
                          const float* __restrict__ r_in, const float* __restrict__ c_in,
                          float* __restrict__ r_out, float* __restrict__ c_out,
                          int fin, int fout) {
  __shared__ float red[256];
  int t = threadIdx.x;
  int jl = t & 31, ig = t >> 5;
  int j = blockIdx.x * 32 + jl;
  int chunk = fout >> 3;
  int i0 = ig * chunk;
  float acc = 0.f;
  for (int i = i0; i < i0 + chunk; ++i)
    acc += r_in[i] * W[(size_t)i * fin + j];
  red[t] = acc;
  __syncthreads();
  if (ig == 0) {
    float s = 0.f;
#pragma unroll
    for (int u = 0; u < 8; ++u) s += red[u * 32 + jl];
    r_out[j] = s;
  }
  if (blockIdx.x == 0) {
    __syncthreads();
    float p = 0.f;
    for (int i = t; i < fout; i += 256) p += r_in[i] * bt[i];
    red[t] = p;
    __syncthreads();
    for (int s = 128; s > 0; s >>= 1) {
      if (t < s) red[t] += red[t + s];
      __syncthreads();
    }
    if (t == 0) c_out[0] = red[0] + c_in[0];
  }
}

// ---------------- final: BN2 (inline) + dot + sigmoid ----------------
__global__ void final_k(const float* __restrict__ C2, const float* __restrict__ SUM2,
                        const float* __restrict__ SQ2, const float* __restrict__ g2,
                        const float* __restrict__ b2, const float* __restrict__ r,
                        const float* __restrict__ c_in, float* __restrict__ out) {
  int n = blockIdx.x;       // 64
  int t = threadIdx.x;      // 256
  float acc = 0.f;
  for (int j = t; j < 3200; j += 256) {
    int c = j / 25, sp = j - c * 25;
    float mean = SUM2[c] * (1.f / 1600.f);
    float var = SQ2[c] * (1.f / 1600.f) - mean * mean;
    float sc = g2[c] / sqrtf(var + 1e-5f);
    float sh = b2[c] - mean * sc;
    float v = C2[((size_t)n * 25 + sp) * 128 + c] * sc + sh;
    acc += v * r[j];
  }
  __shared__ float red[256];
  red[t] = acc;
  __syncthreads();
  for (int s = 128; s > 0; s >>= 1) {
    if (t < s) red[t] += red[t + s];
    __syncthreads();
  }
  if (t == 0) {
    float z = red[0] + c_in[0];
    out[n] = 1.f / (1.f + expf(-z));
  }
}

// ---------------- workspace layout (bytes) ----------------
// A1 region (115.6 MB) is reused after gemm1: C1/A2/C2P/C2 alias into it.
static constexpr size_t OFF_A1   = 0;                    // 115,605,504
static constexpr size_t OFF_C1   = 0;                    // 12,845,056 (after gemm1)
static constexpr size_t OFF_A2   = 16777216;             // 7,372,800
static constexpr size_t OFF_C2P  = 33554432;             // 8 x 819,200
static constexpr size_t OFF_C2   = 41943040;             // 819,200
static constexpr size_t OFF_W1B  = 115605504;            // 2,359,296
static constexpr size_t OFF_W2B  = 117964800;            // 589,824
static constexpr size_t OFF_STATS= 118554624;            // 4096 (SUM1,SQ1,SUM2,SQ2)
static constexpr size_t OFF_RA   = 118558720;            // 13,056
static constexpr size_t OFF_RB   = 118571776;            // 13,056
static constexpr size_t OFF_CA   = 118584832;            // 128
static constexpr size_t OFF_CB   = 118584960;            // 128
static constexpr size_t OFF_C1P  = 118585344;            // ks1 x 12,845,056

extern "C" void kernel_launch(void* const* d_in, const int* in_sizes, int n_in,
                              void* d_out, int out_size, void* d_ws, size_t ws_size,
                              hipStream_t stream) {
  const float* x   = (const float*)d_in[0];
  const float* w1  = (const float*)d_in[1];
  const float* g1  = (const float*)d_in[3];
  const float* bb1 = (const float*)d_in[4];
  const float* w2  = (const float*)d_in[5];
  const float* g2  = (const float*)d_in[7];
  const float* bb2 = (const float*)d_in[8];

  char* ws = (char*)d_ws;
  unsigned short* A1  = (unsigned short*)(ws + OFF_A1);
  float*          C1  = (float*)(ws + OFF_C1);
  unsigned short* A2  = (unsigned short*)(ws + OFF_A2);
  float*          C2P = (float*)(ws + OFF_C2P);
  float*          C2  = (float*)(ws + OFF_C2);
  unsigned short* W1b = (unsigned short*)(ws + OFF_W1B);
  unsigned short* W2b = (unsigned short*)(ws + OFF_W2B);
  float* SUM1 = (float*)(ws + OFF_STATS);
  float* SQ1  = (float*)(ws + OFF_STATS + 1024);
  float* SUM2 = (float*)(ws + OFF_STATS + 2048);
  float* SQ2  = (float*)(ws + OFF_STATS + 3072);
  float* RA   = (float*)(ws + OFF_RA);
  float* RB   = (float*)(ws + OFF_RB);
  float* CA   = (float*)(ws + OFF_CA);
  float* CB   = (float*)(ws + OFF_CB);
  float* C1P  = (float*)(ws + OFF_C1P);

  // K-split factor for conv1 GEMM, limited by workspace size
  const size_t cpart = 12845056;
  int ks1 = (ws_size >= OFF_C1P + 4 * cpart) ? 4
          : (ws_size >= OFF_C1P + 2 * cpart) ? 2 : 1;

  hipMemsetAsync(ws + OFF_STATS, 0, 4096, stream);

  cast2<<<1440, 256, 0, stream>>>(w1, w2, W1b, W2b);

  // conv1 as GEMM (K-split)
  im2col1<<<dim3(8, 14, 64), 256, 0, stream>>>(x, A1);
  gemm_bf16<128><<<dim3(196, 2, ks1), 256, 0, stream>>>(A1, W1b, C1P, 12544, 256, 4608,
                                                        4608 / ks1);
  if (ks1 == 4)
    reduce_stats<4><<<392, 256, 0, stream>>>(C1P, C1, SUM1, SQ1, 32, 256, 3211264);
  else if (ks1 == 2)
    reduce_stats<2><<<392, 256, 0, stream>>>(C1P, C1, SUM1, SQ1, 32, 256, 3211264);
  else
    reduce_stats<1><<<392, 256, 0, stream>>>(C1P, C1, SUM1, SQ1, 32, 256, 3211264);

  // conv2 as GEMM (BN1 applied inline in im2col2; K-split 8)
  im2col2<<<14400, 256, 0, stream>>>(C1, SUM1, SQ1, g1, bb1, A2);
  gemm_bf16<64><<<dim3(25, 2, 8), 256, 0, stream>>>(A2, W2b, C2P, 1600, 128, 2304, 288);
  reduce_stats<8><<<100, 128, 0, stream>>>(C2P, C2, SUM2, SQ2, 16, 128, 204800);

  // MLP composition
  mlp_head<<<1, 256, 0, stream>>>(
      (const float*)d_in[31], (const float*)d_in[32],
      (const float*)d_in[29], (const float*)d_in[30],
      (const float*)d_in[27], (const float*)d_in[28],
      (const float*)d_in[25], (const float*)d_in[26],
      (const float*)d_in[23], (const float*)d_in[24],
      (const float*)d_in[21], (const float*)d_in[22],
      (const float*)d_in[19], (const float*)d_in[20],
      (const float*)d_in[17], (const float*)d_in[18],
      RA, CA);
  mlp_stage<<<16, 256, 0, stream>>>((const float*)d_in[15], (const float*)d_in[16],
                                    RA, CA, RB, CB, 512, 256);
  mlp_stage<<<32, 256, 0, stream>>>((const float*)d_in[13], (const float*)d_in[14],
                                    RB, CB, RA, CA, 1024, 512);
  mlp_stage<<<64, 256, 0, stream>>>((const float*)d_in[11], (const float*)d_in[12],
                                    RA, CA, RB, CB, 2048, 1024);
  mlp_stage<<<100, 256, 0, stream>>>((const float*)d_in[9], (const float*)d_in[10],
                                     RB, CB, RA, CA, 3200, 2048);

  final_k<<<64, 256, 0, stream>>>(C2, SUM2, SQ2, g2, bb2, RA, CA, (float*)d_out);
}